// Round 1
// baseline (302.288 us; speedup 1.0000x reference)
//
#include <hip/hip_runtime.h>

typedef _Float16 f16;
typedef _Float16 f16x8 __attribute__((ext_vector_type(8)));
typedef _Float16 f16x4 __attribute__((ext_vector_type(4)));
typedef float f32x4 __attribute__((ext_vector_type(4)));

#define MFMA16(A, B, C) __builtin_amdgcn_mfma_f32_16x16x32_f16((A), (B), (C), 0, 0, 0)

// async global->LDS, 16B per lane, dest = wave-uniform base + lane*16
__device__ __forceinline__ void async16(void* lds, const void* gp) {
    __builtin_amdgcn_global_load_lds(
        (__attribute__((address_space(1))) void*)(gp),
        (__attribute__((address_space(3))) void*)(lds), 16, 0, 0);
}

// ---------------- fp32 -> fp16 cast (vectorized) ----------------
__global__ __launch_bounds__(256) void k_convert(const float* __restrict__ in,
                                                 f16* __restrict__ out, int n) {
    int i = (blockIdx.x * 256 + threadIdx.x) * 4;
    if (i + 3 < n) {
        float4 v = *(const float4*)(in + i);
        f16x4 o = {(f16)v.x, (f16)v.y, (f16)v.z, (f16)v.w};
        *(f16x4*)(out + i) = o;
    }
}

// ---------------- transpose + cast all four 1024x1024 weights in one launch ----------------
__global__ __launch_bounds__(256) void k_transpose_w4(const float* __restrict__ Wq,
                                                      const float* __restrict__ Wk,
                                                      const float* __restrict__ Wv,
                                                      const float* __restrict__ Wr,
                                                      f16* __restrict__ Wqkvt,
                                                      f16* __restrict__ Wrt) {
    __shared__ float tile[32][33];
    int z = blockIdx.z;
    const float* W = (z == 0) ? Wq : (z == 1) ? Wk : (z == 2) ? Wv : Wr;
    f16* Wt = (z == 3) ? Wrt : Wqkvt + z * 1048576;
    int c0 = blockIdx.x * 32, r0 = blockIdx.y * 32;
    int tx = threadIdx.x, ty = threadIdx.y;  // 32 x 8
#pragma unroll
    for (int j = 0; j < 32; j += 8)
        tile[ty + j][tx] = W[(r0 + ty + j) * 1024 + c0 + tx];
    __syncthreads();
#pragma unroll
    for (int j = 0; j < 32; j += 8)
        Wt[(c0 + ty + j) * 1024 + r0 + tx] = (f16)tile[tx][ty + j];
}

// ---------------- transpose V slice of QKV into Vt[bh][d][s] ----------------
__global__ __launch_bounds__(256) void k_transpose_v(const f16* __restrict__ QKV,
                                                     f16* __restrict__ Vt) {
    __shared__ f16 tile[32][33];
    int s0 = blockIdx.x * 32;
    int d0 = blockIdx.y * 32;
    int bh = blockIdx.z;
    int b = bh >> 4, h = bh & 15;
    int tx = threadIdx.x, ty = threadIdx.y;  // 32 x 8
#pragma unroll
    for (int j = 0; j < 32; j += 8)
        tile[ty + j][tx] = QKV[(b * 2048 + s0 + ty + j) * 3072 + 2048 + h * 64 + d0 + tx];
    __syncthreads();
#pragma unroll
    for (int j = 0; j < 32; j += 8)
        Vt[(bh * 64 + d0 + ty + j) * 2048 + s0 + tx] = tile[tx][ty + j];
}

// ---------------- GEMM: C[M][N] = A[M][K] * Bt[N][K]^T, async-LDS staging ----------------
// 128x128 tile, BK=32, 256 threads. Unpadded LDS; 16B chunk c of row r stored at slot
// c ^ ((r>>1)&3): async writes are lane-contiguous, frag reads per-beat conflict-free.
template <bool OUT_F16>
__global__ __launch_bounds__(256) void k_gemm_bt(const f16* __restrict__ A,
                                                 const f16* __restrict__ Bt,
                                                 void* __restrict__ Cv,
                                                 int M, int N, int K) {
    __shared__ f16 As[128][32];
    __shared__ f16 Bs[128][32];
    int t = threadIdx.x;
    int lane = t & 63, w = t >> 6;
    int wm = (w >> 1) * 64, wn = (w & 1) * 64;
    int m0 = blockIdx.y * 128, n0 = blockIdx.x * 128;
    int ln = lane & 15, g = lane >> 4;

    // async staging map: two 64-chunk instructions per matrix per wave
    int lin0 = w * 128 + lane, lin1 = lin0 + 64;
    int r0 = lin0 >> 2, c0 = (lin0 & 3) ^ ((r0 >> 1) & 3);
    int r1 = lin1 >> 2, c1 = (lin1 & 3) ^ ((r1 >> 1) & 3);
    const f16* gA0 = A + (size_t)(m0 + r0) * K + c0 * 8;
    const f16* gA1 = A + (size_t)(m0 + r1) * K + c1 * 8;
    const f16* gB0 = Bt + (size_t)(n0 + r0) * K + c0 * 8;
    const f16* gB1 = Bt + (size_t)(n0 + r1) * K + c1 * 8;
    f16* lA0 = &As[0][0] + w * 1024;
    f16* lB0 = &Bs[0][0] + w * 1024;

    f32x4 acc[4][4] = {};
    int sw = (ln >> 1) & 3;

    for (int k0 = 0; k0 < K; k0 += 32) {
        __syncthreads();
        async16(lA0, gA0 + k0);
        async16(lA0 + 512, gA1 + k0);
        async16(lB0, gB0 + k0);
        async16(lB0 + 512, gB1 + k0);
        __syncthreads();
        f16x8 af[4], bf[4];
#pragma unroll
        for (int i = 0; i < 4; i++) {
            af[i] = *(const f16x8*)&As[wm + i * 16 + ln][(g ^ sw) * 8];
            bf[i] = *(const f16x8*)&Bs[wn + i * 16 + ln][(g ^ sw) * 8];
        }
#pragma unroll
        for (int mt = 0; mt < 4; mt++)
#pragma unroll
            for (int nt = 0; nt < 4; nt++)
                acc[mt][nt] = MFMA16(af[mt], bf[nt], acc[mt][nt]);
    }

    int rg = g * 4;
#pragma unroll
    for (int mt = 0; mt < 4; mt++)
#pragma unroll
        for (int nt = 0; nt < 4; nt++)
#pragma unroll
            for (int r = 0; r < 4; r++) {
                int row = m0 + wm + mt * 16 + rg + r;
                int col = n0 + wn + nt * 16 + ln;
                float v = acc[mt][nt][r];
                if (OUT_F16)
                    ((f16*)Cv)[(size_t)row * N + col] = (f16)v;
                else
                    ((float*)Cv)[(size_t)row * N + col] = v;
            }
}

// ---------------- flash attention v4: split-k for occupancy ----------------
// Fixed-max-0 softmax => partial numerators/rowsums are exactly additive => split-k is
// a trivially mergeable decomposition. Each q-tile's k-range is halved; block pi handles
// (qt=15-pi, half 0: kt 0..15-pi) then (qt=pi, half 1: kt pi+1..2pi+1) -> 1024 uniform
// blocks of 17 k-tiles, all co-resident at 4 blocks/CU (was 2) -> double waves/SIMD.
// Each unit writes normalized f16 partial O + f32 rowsum; k_merge recombines.
__global__ __launch_bounds__(256, 4) void k_attn(const f16* __restrict__ QKV,
                                                 const f16* __restrict__ Vt,
                                                 f16* __restrict__ Opart,
                                                 float* __restrict__ Rsum) {
    __shared__ f16 Ks[64][72];
    __shared__ f16 Vs[64][72];   // V^T tile: [d][k]
    __shared__ f16 Ps[128][72];  // P in [q][k], wave-private rows
    int pi = blockIdx.x, bh = blockIdx.y;  // pi 0..15
    int b = bh >> 4, h = bh & 15;
    int t = threadIdx.x, lane = t & 63, wq = t >> 6;
    int ln = lane & 15, g = lane >> 4, g8 = g * 8, rg = g * 4;

    // staging coords: two K chunks + two V chunks per thread per tile
    int c0 = t, c1 = t + 256;
    int kr0 = c0 >> 3, kc0 = (c0 & 7) * 8;
    int kr1 = c1 >> 3, kc1 = (c1 & 7) * 8;
    const f16* Kbase = QKV + (size_t)b * 2048 * 3072 + 1024 + h * 64;
    const f16* Vbase = Vt + (size_t)bh * 64 * 2048;

    const float C_SCL = 0.18033688f;   // 0.125 * log2(e)
    const float C_MSK = -72.134752f;   // -50 * log2(e)
    f16x8 ones;
#pragma unroll
    for (int j = 0; j < 8; j++) ones[j] = (f16)1.f;

    // initial prefetch: phase 0, first tile (kt=0)
    int4 rk0 = *(const int4*)(Kbase + (size_t)kr0 * 3072 + kc0);
    int4 rk1 = *(const int4*)(Kbase + (size_t)kr1 * 3072 + kc1);
    int4 rv0 = *(const int4*)(Vbase + (size_t)kr0 * 2048 + kc0);
    int4 rv1 = *(const int4*)(Vbase + (size_t)kr1 * 2048 + kc1);

    for (int phase = 0; phase < 2; phase++) {
        int qt  = phase ? pi : 15 - pi;
        int ktB = phase ? pi + 1 : 0;
        int ktE = phase ? 2 * pi + 2 : 16 - pi;
        int q0 = qt * 128;

        f16x8 bq[2][2];
#pragma unroll
        for (int nt = 0; nt < 2; nt++)
#pragma unroll
            for (int kd = 0; kd < 2; kd++)
                bq[nt][kd] = *(const f16x8*)(QKV +
                    (size_t)(b * 2048 + q0 + wq * 32 + nt * 16 + ln) * 3072 +
                    h * 64 + kd * 32 + g8);

        f32x4 oacc[2][4] = {};
        f32x4 osum[2] = {};

        for (int kt = ktB; kt < ktE; kt++) {
            int k0 = kt * 64;
            __syncthreads();  // all waves done reading LDS from previous tile
            *(int4*)&Ks[kr0][kc0] = rk0;
            *(int4*)&Ks[kr1][kc1] = rk1;
            *(int4*)&Vs[kr0][kc0] = rv0;
            *(int4*)&Vs[kr1][kc1] = rv1;
            if (kt + 1 < ktE) {  // prefetch next tile of this unit
                int kn = k0 + 64;
                rk0 = *(const int4*)(Kbase + (size_t)(kn + kr0) * 3072 + kc0);
                rk1 = *(const int4*)(Kbase + (size_t)(kn + kr1) * 3072 + kc1);
                rv0 = *(const int4*)(Vbase + (size_t)kr0 * 2048 + kn + kc0);
                rv1 = *(const int4*)(Vbase + (size_t)kr1 * 2048 + kn + kc1);
            } else if (phase == 0) {  // prefetch phase 1, first tile (kt = pi+1)
                int kn = (pi + 1) * 64;
                rk0 = *(const int4*)(Kbase + (size_t)(kn + kr0) * 3072 + kc0);
                rk1 = *(const int4*)(Kbase + (size_t)(kn + kr1) * 3072 + kc1);
                rv0 = *(const int4*)(Vbase + (size_t)kr0 * 2048 + kn + kc0);
                rv1 = *(const int4*)(Vbase + (size_t)kr1 * 2048 + kn + kc1);
            }
            __syncthreads();

            // tile fully above this wave's diagonal -> contributes ~e^-50 ~ 0
            if (k0 > q0 + wq * 32 + 31) continue;  // wave-uniform; barriers outside

            // S^T tile: D[m=k][n=q]
            f32x4 sacc[4][2] = {};
#pragma unroll
            for (int kd = 0; kd < 2; kd++) {
                f16x8 ak[4];
#pragma unroll
                for (int mt = 0; mt < 4; mt++)
                    ak[mt] = *(const f16x8*)&Ks[mt * 16 + ln][kd * 32 + g8];
#pragma unroll
                for (int mt = 0; mt < 4; mt++)
#pragma unroll
                    for (int nt = 0; nt < 2; nt++)
                        sacc[mt][nt] = MFMA16(ak[mt], bq[nt][kd], sacc[mt][nt]);
            }

            // softmax numerator (fixed max 0): lane has q=..+ln, k=..+rg+r (4 consecutive)
            bool needs_mask = (k0 + 63 > q0 + wq * 32);
#pragma unroll
            for (int nt = 0; nt < 2; nt++) {
                int q = q0 + wq * 32 + nt * 16 + ln;
#pragma unroll
                for (int mt = 0; mt < 4; mt++) {
                    f16x4 pk;
#pragma unroll
                    for (int r = 0; r < 4; r++) {
                        float e;
                        if (needs_mask) {
                            int kk = k0 + mt * 16 + rg + r;
                            e = __builtin_amdgcn_exp2f(
                                fmaf(sacc[mt][nt][r], C_SCL, (kk > q) ? C_MSK : 0.f));
                        } else {
                            e = __builtin_amdgcn_exp2f(sacc[mt][nt][r] * C_SCL);
                        }
                        pk[r] = (f16)e;
                    }
                    *(f16x4*)&Ps[wq * 32 + nt * 16 + ln][mt * 16 + rg] = pk;
                }
            }

            // O += P.V ; rowsum += P.1  (Ps wave-private: intra-wave lgkm ordering suffices)
#pragma unroll
            for (int kk = 0; kk < 2; kk++) {
                f16x8 ap[2], bv[4];
#pragma unroll
                for (int mt = 0; mt < 2; mt++)
                    ap[mt] = *(const f16x8*)&Ps[wq * 32 + mt * 16 + ln][kk * 32 + g8];
#pragma unroll
                for (int dt = 0; dt < 4; dt++)
                    bv[dt] = *(const f16x8*)&Vs[dt * 16 + ln][kk * 32 + g8];
#pragma unroll
                for (int mt = 0; mt < 2; mt++) {
#pragma unroll
                    for (int dt = 0; dt < 4; dt++)
                        oacc[mt][dt] = MFMA16(ap[mt], bv[dt], oacc[mt][dt]);
                    osum[mt] = MFMA16(ap[mt], ones, osum[mt]);
                }
            }
        }

        // epilogue: write normalized partial + rowsum. osum C-layout row = 4g+r matches
        // oacc rows exactly. Rows with zero partial (fully-skipped) guarded -> 0.
        int u = (bh * 16 + qt) * 2 + phase;
#pragma unroll
        for (int mt = 0; mt < 2; mt++)
#pragma unroll
            for (int r = 0; r < 4; r++) {
                float rs = osum[mt][r];
                float inv = __builtin_amdgcn_rcpf(fmaxf(rs, 1e-30f));
                int q = wq * 32 + mt * 16 + rg + r;
                if (ln == 0) Rsum[u * 128 + q] = rs;
#pragma unroll
                for (int dt = 0; dt < 4; dt++)
                    Opart[(size_t)u * 8192 + q * 64 + dt * 16 + ln] =
                        (f16)(oacc[mt][dt][r] * inv);
            }
    }
}

// ---------------- merge split-k partials: O = (rs0*O0 + rs1*O1)/(rs0+rs1) ----------------
__global__ __launch_bounds__(256) void k_merge(const f16* __restrict__ Op,
                                               const float* __restrict__ Rs,
                                               f16* __restrict__ Ob) {
    int idx = blockIdx.x * 256 + threadIdx.x;  // 64bh*16qt*128q*8chunks = 1,048,576
    int d8 = idx & 7;
    int q  = (idx >> 3) & 127;
    int qt = (idx >> 10) & 15;
    int bh = idx >> 14;
    int b = bh >> 4, hd = bh & 15;
    int u0 = (bh * 16 + qt) * 2;
    float rs0 = Rs[u0 * 128 + q], rs1 = Rs[(u0 + 1) * 128 + q];
    float inv = __builtin_amdgcn_rcpf(rs0 + rs1);  // rs0 > 0 always (diagonal in half 0)
    f16x8 o0 = *(const f16x8*)(Op + (size_t)u0 * 8192 + q * 64 + d8 * 8);
    f16x8 o1 = *(const f16x8*)(Op + (size_t)(u0 + 1) * 8192 + q * 64 + d8 * 8);
    f16x8 o;
#pragma unroll
    for (int j = 0; j < 8; j++)
        o[j] = (f16)((rs0 * (float)o0[j] + rs1 * (float)o1[j]) * inv);
    *(f16x8*)(Ob + (size_t)(b * 2048 + qt * 128 + q) * 1024 + hd * 64 + d8 * 8) = o;
}

// ---------------- host launch ----------------
extern "C" void kernel_launch(void* const* d_in, const int* in_sizes, int n_in,
                              void* d_out, int out_size, void* d_ws, size_t ws_size,
                              hipStream_t stream) {
    const float* x = (const float*)d_in[0];
    const float* Wq = (const float*)d_in[1];
    const float* Wk = (const float*)d_in[2];
    const float* Wv = (const float*)d_in[3];
    const float* Wr = (const float*)d_in[4];
    float* out = (float*)d_out;

    f16* ws = (f16*)d_ws;
    f16* xb    = ws;                    // 8192*1024
    f16* Wqkvt = xb + 8388608;          // 3072*1024
    f16* Wrt   = Wqkvt + 3145728;       // 1024*1024
    f16* QKVb  = Wrt + 1048576;         // 8192*3072
    f16* Vtb   = QKVb + 25165824;       // 64bh * 64d * 2048s
    f16* Obuf  = Vtb + 8388608;         // 8192*1024
    f16* Opart = Obuf + 8388608;        // 2048 units * 128q * 64d
    float* Rsum = (float*)(Opart + 16777216);  // 2048 units * 128q

    k_convert<<<8192, 256, 0, stream>>>(x, xb, 8388608);
    dim3 tb(32, 8);
    k_transpose_w4<<<dim3(32, 32, 4), tb, 0, stream>>>(Wq, Wk, Wv, Wr, Wqkvt, Wrt);
    k_gemm_bt<true><<<dim3(24, 64), 256, 0, stream>>>(xb, Wqkvt, QKVb, 8192, 3072, 1024);
    k_transpose_v<<<dim3(64, 2, 64), tb, 0, stream>>>(QKVb, Vtb);
    k_attn<<<dim3(16, 64), 256, 0, stream>>>(QKVb, Vtb, Opart, Rsum);
    k_merge<<<4096, 256, 0, stream>>>(Opart, Rsum, Obuf);
    k_gemm_bt<false><<<dim3(8, 64), 256, 0, stream>>>(Obuf, Wrt, out, 8192, 1024, 1024);
}